// Round 17
// baseline (253.264 us; speedup 1.0000x reference)
//
#include <hip/hip_runtime.h>

#define K_2RPI   1.1283791670955126f   // 2/sqrt(pi)
#define LN2F     0.6931471805599453f
#define PI_2F    1.5707963267948966f
#define PIF      3.14159265358979323846f

// atan minimax odd poly on [0,1]: FULL A&S 4.4.49 (5 terms, degree-9), |err| <= 1e-5
__device__ __forceinline__ float atan_poly01(float r) {
    const float r2 = r * r;
    float p = fmaf(r2,  0.0208351f, -0.0851330f);
    p = fmaf(r2, p,  0.1801410f);
    p = fmaf(r2, p, -0.3302995f);
    p = fmaf(r2, p,  0.9998660f);
    return p * r;
}

// ---------------------------------------------------------------------------
// Pre-kernel: per-(b,i) uniform math, a-NORMALIZED: F(a,b,c) = |a|*F(1,b/|a|,c/|a|).
// ws[(b*N+i)*8 + {0..7}] = U1,U2,V1,V2, rlxa, rlya, PL, PTn   (all /|a| scaled)
// ws[B*N*8 + b]          = SPB[b] = B_off * A * sum_i cp[b,i]
// ---------------------------------------------------------------------------
__global__ void chiplet_pre_kernel(const float* __restrict__ cx, const float* __restrict__ cy,
                                   const float* __restrict__ cw, const float* __restrict__ chh,
                                   const float* __restrict__ cp,
                                   const float* __restrict__ pA, const float* __restrict__ pa,
                                   const float* __restrict__ pB,
                                   const float* __restrict__ lx, const float* __restrict__ ly,
                                   float* __restrict__ ws, int B, int N)
{
    const int t = blockIdx.x * blockDim.x + threadIdx.x;
    if (t >= B * N) return;
    const int b = t / N;
    const int i = t - b * N;

    const float Av   = pA[0];
    const float av   = pa[0];
    const float Boff = pB[0];
    const float aa   = fabsf(av);

    const float rlxa = 1.0f / (lx[i] * aa);
    const float rlya = 1.0f / (ly[i] * aa);
    const float w2  = 0.5f * cw[t];
    const float h2  = 0.5f * chh[t];
    const float cxi = cx[t];
    const float cyi = cy[t];
    const float PiA = cp[t] * Av;

    float* o = ws + (size_t)t * 8;
    o[0] = (w2 + cxi) * rlxa;           // U1
    o[1] = (w2 - cxi) * rlxa;           // U2
    o[2] = (h2 + cyi) * rlya;           // V1
    o[3] = (h2 - cyi) * rlya;           // V2
    o[4] = rlxa;
    o[5] = rlya;
    o[6] = PiA * (K_2RPI * LN2F) * aa;  // PL
    o[7] = -(PiA * K_2RPI) * aa;        // PTn

    if (i == 0) {
        float s = 0.0f;
        for (int j = 0; j < N; ++j) s += cp[b * N + j];
        ws[(size_t)B * N * 8 + b] = s * Av * Boff;   // SPB[b]
    }
}

// ---------------------------------------------------------------------------
// Per-point-per-chiplet body (a==1): log ratio form + complex-pair atan,
// one v_rcp per point per chiplet.
// ---------------------------------------------------------------------------
__device__ __forceinline__ void chiplet_point(
    float xv, float yv,
    float U1, float U2, float V1, float V2,
    float rlx, float rly, float PL, float PTn,
    float& acc)
{
    const float b1 = fmaf(-xv, rlx, U1);
    const float b2 = fmaf( xv, rlx, U2);
    const float c1 = fmaf(-yv, rly, V1);
    const float c2 = fmaf( yv, rly, V2);

    const float sb1 = fmaf(b1, b1, 1.0f);
    const float sb2 = fmaf(b2, b2, 1.0f);
    const float cq1 = c1 * c1;
    const float cq2 = c2 * c2;

    const float d11 = __builtin_amdgcn_sqrtf(sb1 + cq1);
    const float d12 = __builtin_amdgcn_sqrtf(sb1 + cq2);
    const float d21 = __builtin_amdgcn_sqrtf(sb2 + cq1);
    const float d22 = __builtin_amdgcn_sqrtf(sb2 + cq2);

    const float n11 = b1 * c1, n12 = b1 * c2;
    const float n21 = b2 * c1, n22 = b2 * c2;

    const float reA = fmaf(-n11, n12, d11 * d12);
    const float imA = fmaf( d11, n12, n11 * d12);
    const float reB = fmaf(-n21, n22, d21 * d22);
    const float imB = fmaf( d21, n22, n21 * d22);

    const float ayA = fabsf(imA), axA = fabsf(reA);
    const float ayB = fabsf(imB), axB = fabsf(reB);
    const float hA = fmaxf(ayA, axA), lA = fminf(ayA, axA);
    const float hB = fmaxf(ayB, axB), lB = fminf(ayB, axB);

    const float nu1 = c2 + d12, nu2 = c2 + d22;
    const float nu3 = b2 + d21, nu4 = b2 + d22;
    const float de1 = d11 - c1, de2 = d21 - c1;
    const float de3 = d11 - b1, de4 = d12 - b1;

    const float p12 = de1 * de2, p34 = de3 * de4;

    const float G = p12 * p34;
    const float H = hA * hB;
    const float RC = __builtin_amdgcn_rcpf(G * H);
    const float R  = RC * H;          // 1/G
    const float R2 = RC * G;          // 1/H

    const float R12 = R * p34, R34 = R * p12;
    const float r1 = R12 * de2, r2 = R12 * de1;
    const float r3 = R34 * de4, r4 = R34 * de3;

    float logsum =      b1 * __log2f(nu1 * r1);
    logsum = fmaf(b2, __log2f(nu2 * r2), logsum);
    logsum = fmaf(c1, __log2f(nu3 * r3), logsum);
    logsum = fmaf(c2, __log2f(nu4 * r4), logsum);

    const float tA = lA * (R2 * hB);
    const float tB = lB * (R2 * hA);

    const float pA_ = atan_poly01(tA);
    const float pB_ = atan_poly01(tB);

    float angA = (ayA > axA) ? (PI_2F - pA_) : pA_;
    angA = (reA < 0.0f) ? (PIF - angA) : angA;
    angA = __builtin_copysignf(angA, imA);

    float angB = (ayB > axB) ? (PI_2F - pB_) : pB_;
    angB = (reB < 0.0f) ? (PIF - angB) : angB;
    angB = __builtin_copysignf(angB, imB);

    const float atansum = angA + angB;

    acc = fmaf(PL,  logsum,  acc);
    acc = fmaf(PTn, atansum, acc);
}

// ---------------------------------------------------------------------------
// Main kernel: FOUR grid points per thread (float4), shared per-chiplet uniforms.
// ---------------------------------------------------------------------------
template <int NT>
__global__ __launch_bounds__(256)
void chiplet_main4_kernel(const float* __restrict__ x, const float* __restrict__ y,
                          const float* __restrict__ ws,
                          float* __restrict__ out, int n_rt, int G2, int B)
{
    const int b  = blockIdx.y;
    const int g  = blockIdx.x * blockDim.x + threadIdx.x;   // quad index
    const int quarter = G2 >> 2;
    if (g >= quarter) return;
    const int pidx = b * quarter + g;
    const int n = (NT > 0) ? NT : n_rt;

    const float4 xv4 = ((const float4*)x)[pidx];
    const float4 yv4 = ((const float4*)y)[pidx];
    const float xv[4] = { xv4.x, xv4.y, xv4.z, xv4.w };
    const float yv[4] = { yv4.x, yv4.y, yv4.z, yv4.w };

    const float spb = ws[(size_t)B * n * 8 + b];
    float acc[4] = { spb, spb, spb, spb };

#pragma unroll
    for (int i = 0; i < n; ++i) {
        const float* o = ws + (size_t)(b * n + i) * 8;   // uniform -> s_load_dwordx8
        const float U1  = o[0], U2  = o[1], V1 = o[2], V2 = o[3];
        const float rlx = o[4], rly = o[5], PL = o[6], PTn = o[7];

#pragma unroll
        for (int k = 0; k < 4; ++k) {
            chiplet_point(xv[k], yv[k], U1, U2, V1, V2, rlx, rly, PL, PTn, acc[k]);
        }
    }

    ((float4*)out)[pidx] = make_float4(acc[0], acc[1], acc[2], acc[3]);
}

// Generic 1-point fallback (any N, any G2)
template <int NT>
__global__ __launch_bounds__(256)
void chiplet_main1_kernel(const float* __restrict__ x, const float* __restrict__ y,
                          const float* __restrict__ ws,
                          float* __restrict__ out, int n_rt, int G2, int B)
{
    const int b = blockIdx.y;
    const int g = blockIdx.x * blockDim.x + threadIdx.x;
    if (g >= G2) return;
    const int idx = b * G2 + g;
    const int n = (NT > 0) ? NT : n_rt;

    const float xv = x[idx];
    const float yv = y[idx];
    float acc = ws[(size_t)B * n * 8 + b];

    for (int i = 0; i < n; ++i) {
        const float* o = ws + (size_t)(b * n + i) * 8;
        chiplet_point(xv, yv, o[0], o[1], o[2], o[3], o[4], o[5], o[6], o[7], acc);
    }
    out[idx] = acc;
}

extern "C" void kernel_launch(void* const* d_in, const int* in_sizes, int n_in,
                              void* d_out, int out_size, void* d_ws, size_t ws_size,
                              hipStream_t stream) {
    const float* x   = (const float*)d_in[0];
    const float* y   = (const float*)d_in[1];
    const float* cx  = (const float*)d_in[2];
    const float* cy  = (const float*)d_in[3];
    const float* cw  = (const float*)d_in[4];
    const float* chh = (const float*)d_in[5];
    const float* cp  = (const float*)d_in[6];
    const float* pA  = (const float*)d_in[7];
    const float* pa  = (const float*)d_in[8];
    const float* pB  = (const float*)d_in[9];
    const float* lx  = (const float*)d_in[10];
    const float* ly  = (const float*)d_in[11];
    float* out = (float*)d_out;
    float* ws  = (float*)d_ws;

    const int N  = in_sizes[10];            // lx has N elements
    const int B  = in_sizes[2] / N;         // chiplets_x is (B, N)
    const int G2 = in_sizes[0] / B;         // x is (B, G2)

    // precompute per-(b,i) uniforms (a-normalized)
    {
        const int total = B * N;
        dim3 pb(256, 1, 1);
        dim3 pg((total + 255) / 256, 1, 1);
        chiplet_pre_kernel<<<pg, pb, 0, stream>>>(cx, cy, cw, chh, cp,
                                                  pA, pa, pB, lx, ly, ws, B, N);
    }

    if (N == 16 && (G2 % 4) == 0) {
        const int quarter = G2 / 4;
        dim3 block(256, 1, 1);
        dim3 grid((quarter + 255) / 256, B, 1);
        chiplet_main4_kernel<16><<<grid, block, 0, stream>>>(x, y, ws, out, N, G2, B);
    } else {
        dim3 block(256, 1, 1);
        dim3 grid((G2 + 255) / 256, B, 1);
        chiplet_main1_kernel<0><<<grid, block, 0, stream>>>(x, y, ws, out, N, G2, B);
    }
}